// Round 10
// baseline (518.311 us; speedup 1.0000x reference)
//
#include <hip/hip_runtime.h>
#include <hip/hip_cooperative_groups.h>
#include <hip/hip_fp16.h>

namespace cg = cooperative_groups;

#define IN_DIM 128
#define OUT_DIM 64
#define MAXDEG 64      // padded-CSR stride; deg ~ Poisson(16), P(>=64)*N ~ 1e-13
#define COOP_BLKS 1024 // 4 blocks/CU x 256 CUs (launch_bounds(256,4)); clamped by occupancy

typedef __attribute__((ext_vector_type(8))) short short8v;   // 8 bf16 (4 VGPRs)
typedef __attribute__((ext_vector_type(4))) float float4v;   // MFMA acc
typedef unsigned short ushort_t;
typedef unsigned int uint_t;

__device__ inline ushort_t f_to_bf16(float f) {
    uint_t x = __float_as_uint(f);
    uint_t r = (x + 0x7fffu + ((x >> 16) & 1u)) >> 16;   // RNE
    return (ushort_t)r;
}

// ---- shared phase implementations -----------------------------------------

__device__ __forceinline__ void stage_W_lds(const float* __restrict__ W,
                                            ushort_t* Wl, int t)
{
    // Swizzle W into MFMA B-fragment layout: frag=kb*4+db;
    // entry(frag,lane,j) = W[kb*32 + (lane>>4)*8 + j][db*16 + (lane&15)]
    int f = t * 32;
    #pragma unroll
    for (int i = 0; i < 32; i++, f++) {
        int frag = f >> 9;
        int ln   = (f >> 3) & 63;
        int j    = f & 7;
        int k    = (frag >> 2) * 32 + (ln >> 4) * 8 + j;
        int d    = (frag & 3) * 16 + (ln & 15);
        Wl[f] = f_to_bf16(W[k * OUT_DIM + d]);
    }
}

__device__ __forceinline__ void phase_hist(
    const int* __restrict__ dst, int* __restrict__ cnt,
    int* __restrict__ rank, int E, int gtid, int nth)
{
    const int nq = E >> 2;
    for (int q = gtid; q < nq; q += nth) {
        int base = q << 2;
        int4 d4 = *(const int4*)&dst[base];
        int r0 = atomicAdd(&cnt[d4.x], 1);
        int r1 = atomicAdd(&cnt[d4.y], 1);
        int r2 = atomicAdd(&cnt[d4.z], 1);
        int r3 = atomicAdd(&cnt[d4.w], 1);
        *(int4*)&rank[base] = make_int4(r0, r1, r2, r3);
    }
    int rem = E & 3, base = nq << 2;
    if (gtid < rem) rank[base + gtid] = atomicAdd(&cnt[dst[base + gtid]], 1);
}

__device__ __forceinline__ void phase_proj(
    const float* __restrict__ h, const ushort_t* Wl,
    const float* __restrict__ Wb, const float* __restrict__ Aw,
    ushort_t* __restrict__ Whb, float* __restrict__ a_dst_arr,
    float* __restrict__ a_src_arr, int N, int lane, int tile0, int tstride)
{
    // MFMA layouts (m89-verified): A[m=lane&15][k=quad*8+j],
    // B[k=quad*8+j][n=lane&15], C/D col=lane&15, row=quad*4+reg.
    const int quad = lane >> 4;
    const int col  = lane & 15;
    const int ntiles = (N + 15) >> 4;
    for (int tile = tile0; tile < ntiles; tile += tstride) {
        const int node0 = tile * 16;
        const int rowc = min(node0 + col, N - 1);   // clamp for ragged tail
        const float* __restrict__ arow = h + (size_t)rowc * IN_DIM;

        float4v acc[4];
        #pragma unroll
        for (int db = 0; db < 4; db++) acc[db] = (float4v){0.f, 0.f, 0.f, 0.f};

        #pragma unroll
        for (int kb = 0; kb < 4; kb++) {
            const float* ap = arow + kb * 32 + quad * 8;
            float4 a0 = *(const float4*)ap;
            float4 a1 = *(const float4*)(ap + 4);
            union { short8v v; ushort_t u[8]; } af;
            af.u[0] = f_to_bf16(a0.x); af.u[1] = f_to_bf16(a0.y);
            af.u[2] = f_to_bf16(a0.z); af.u[3] = f_to_bf16(a0.w);
            af.u[4] = f_to_bf16(a1.x); af.u[5] = f_to_bf16(a1.y);
            af.u[6] = f_to_bf16(a1.z); af.u[7] = f_to_bf16(a1.w);
            #pragma unroll
            for (int db = 0; db < 4; db++) {
                short8v bf = *(const short8v*)&Wl[(((kb << 2) | db) * 64 + lane) * 8];
                acc[db] = __builtin_amdgcn_mfma_f32_16x16x32_bf16(af.v, bf, acc[db], 0, 0, 0);
            }
        }

        float pd[4] = {0.f, 0.f, 0.f, 0.f};
        float ps[4] = {0.f, 0.f, 0.f, 0.f};
        #pragma unroll
        for (int db = 0; db < 4; db++) {
            float wbv = Wb[db * 16 + col];
            float awd = Aw[db * 16 + col];
            float aws = Aw[OUT_DIM + db * 16 + col];
            #pragma unroll
            for (int r = 0; r < 4; r++) {
                float v = acc[db][r] + wbv;
                int node = node0 + quad * 4 + r;
                if (node < N)
                    Whb[(size_t)node * OUT_DIM + db * 16 + col] = f_to_bf16(v);
                pd[r] = fmaf(v, awd, pd[r]);
                ps[r] = fmaf(v, aws, ps[r]);
            }
        }
        #pragma unroll
        for (int r = 0; r < 4; r++) {
            float d_ = pd[r], s_ = ps[r];
            #pragma unroll
            for (int off = 1; off < 16; off <<= 1) {
                d_ += __shfl_xor(d_, off);
                s_ += __shfl_xor(s_, off);
            }
            int node = node0 + quad * 4 + r;
            if (col == 0 && node < N) {
                a_dst_arr[node] = d_;
                a_src_arr[node] = s_;
            }
        }
    }
}

__device__ __forceinline__ void phase_scatter(
    const int* __restrict__ src, const int* __restrict__ dst,
    const int* __restrict__ rank,
    const float* __restrict__ a_dst_arr, const float* __restrict__ a_src_arr,
    float ab, uint_t* __restrict__ csr, int E, int gtid, int nth)
{
    const int nq = E >> 2;
    for (int q = gtid; q < nq; q += nth) {
        int base = q << 2;
        int4 s4 = *(const int4*)&src[base];
        int4 t4 = *(const int4*)&dst[base];
        int4 k4 = *(const int4*)&rank[base];
        int ss[4] = {s4.x, s4.y, s4.z, s4.w};
        int tt[4] = {t4.x, t4.y, t4.z, t4.w};
        int kk[4] = {k4.x, k4.y, k4.z, k4.w};
        #pragma unroll
        for (int i = 0; i < 4; i++) {
            float v = a_dst_arr[tt[i]] + a_src_arr[ss[i]] + ab;
            v = (v > 0.0f) ? v : 0.2f * v;
            float x = __expf(v);
            uint_t rec = (((uint_t)__half_as_ushort(__float2half(x))) << 16)
                       | (uint_t)(ss[i] & 0xffff);
            csr[tt[i] * MAXDEG + kk[i]] = rec;
        }
    }
    int rem = E & 3, base = nq << 2;
    if (gtid < rem) {
        int e = base + gtid;
        int s = src[e], tt = dst[e];
        float v = a_dst_arr[tt] + a_src_arr[s] + ab;
        v = (v > 0.0f) ? v : 0.2f * v;
        float x = __expf(v);
        uint_t rec = (((uint_t)__half_as_ushort(__float2half(x))) << 16)
                   | (uint_t)(s & 0xffff);
        csr[tt * MAXDEG + rank[e]] = rec;
    }
}

__device__ __forceinline__ void phase_agg(
    const int* __restrict__ cnt, const uint_t* __restrict__ csr,
    const uint_t* __restrict__ Whb2, float* __restrict__ out,
    int N, int wave0, int wstride, int lane)
{
    const int el = lane >> 5;   // edge slot within step
    const int dl = lane & 31;   // dim pair (dims 2*dl, 2*dl+1)
    for (int node = wave0; node < N; node += wstride) {
        int deg = cnt[node];
        const uint_t* __restrict__ seg = csr + (size_t)node * MAXDEG;

        float accx = 0.f, accy = 0.f, wsum = 0.f;
        int j = 0;
        for (; j + 8 <= deg; j += 8) {
            #pragma unroll
            for (int b = 0; b < 4; b++) {
                uint_t r = seg[j + b * 2 + el];
                int   s = (int)(r & 0xffffu);
                float w = __half2float(__ushort_as_half((ushort_t)(r >> 16)));
                uint_t p = Whb2[(size_t)s * 32 + dl];
                float fx = __uint_as_float(p << 16);
                float fy = __uint_as_float(p & 0xffff0000u);
                accx = fmaf(w, fx, accx);
                accy = fmaf(w, fy, accy);
                wsum += w;
            }
        }
        for (; j < deg; j += 2) {
            int e = j + el;
            if (e < deg) {
                uint_t r = seg[e];
                int   s = (int)(r & 0xffffu);
                float w = __half2float(__ushort_as_half((ushort_t)(r >> 16)));
                uint_t p = Whb2[(size_t)s * 32 + dl];
                float fx = __uint_as_float(p << 16);
                float fy = __uint_as_float(p & 0xffff0000u);
                accx = fmaf(w, fx, accx);
                accy = fmaf(w, fy, accy);
                wsum += w;
            }
        }

        accx += __shfl_xor(accx, 32);
        accy += __shfl_xor(accy, 32);
        wsum += __shfl_xor(wsum, 32);

        float inv = (deg > 0) ? 1.0f / wsum : 0.0f;
        if (lane < 32) {
            float2 o = make_float2(accx * inv, accy * inv);
            *(float2*)&out[(size_t)node * OUT_DIM + dl * 2] = o;
        }
    }
}

// ---- cooperative single-kernel path ---------------------------------------

__global__ __launch_bounds__(256, 4) void gat_all(
    const float* __restrict__ h, const float* __restrict__ W,
    const float* __restrict__ Wb, const float* __restrict__ Aw,
    const float* __restrict__ Ab,
    const int* __restrict__ src, const int* __restrict__ dst,
    ushort_t* __restrict__ Whb, float* __restrict__ a_dst_arr,
    float* __restrict__ a_src_arr, int* __restrict__ cnt,
    int* __restrict__ rank, uint_t* __restrict__ csr,
    float* __restrict__ out, int N, int E)
{
    cg::grid_group gg = cg::this_grid();
    __shared__ ushort_t Wl[16 * 64 * 8];   // 16 KB

    const int t    = threadIdx.x;
    const int bid  = (int)blockIdx.x;
    const int nbk  = (int)gridDim.x;
    const int lane = t & 63;
    const int wv   = t >> 6;

    // P0: zero cnt + stage W.
    for (int i = bid * 256 + t; i < N; i += nbk * 256) cnt[i] = 0;
    stage_W_lds(W, Wl, t);
    __syncthreads();
    __threadfence();
    gg.sync();

    // P1: hist+rank (atomic latency) overlapped with MFMA proj across waves.
    phase_hist(dst, cnt, rank, E, bid * 256 + t, nbk * 256);
    phase_proj(h, Wl, Wb, Aw, Whb, a_dst_arr, a_src_arr, N, lane,
               bid * 4 + wv, nbk * 4);
    __threadfence();
    gg.sync();

    // P2: atomic-free padded-CSR scatter.
    phase_scatter(src, dst, rank, a_dst_arr, a_src_arr, Ab[0], csr, E,
                  bid * 256 + t, nbk * 256);
    __threadfence();
    gg.sync();

    // P3: gather-aggregate.
    phase_agg(cnt, csr, (const uint_t*)Whb, out, N, bid * 4 + wv, nbk * 4, lane);
}

// ---- fallback multi-kernel path (R8 structure, known-good) ----------------

__global__ __launch_bounds__(256) void k_fused(
    const float* __restrict__ h, const float* __restrict__ W,
    const float* __restrict__ Wb, const float* __restrict__ Aw,
    ushort_t* __restrict__ Whb, float* __restrict__ a_dst_arr,
    float* __restrict__ a_src_arr, int N,
    const int* __restrict__ dst, int* __restrict__ cnt,
    int* __restrict__ rank, int E, int HB)
{
    __shared__ ushort_t Wl[16 * 64 * 8];
    const int t = threadIdx.x;
    if ((int)blockIdx.x < HB) {
        phase_hist(dst, cnt, rank, E, (int)blockIdx.x * 256 + t, HB * 256);
        return;
    }
    stage_W_lds(W, Wl, t);
    __syncthreads();
    int pb = (int)blockIdx.x - HB;
    int PB = (int)gridDim.x - HB;
    phase_proj(h, Wl, Wb, Aw, Whb, a_dst_arr, a_src_arr, N, t & 63,
               pb * 4 + (t >> 6), PB * 4);
}

__global__ __launch_bounds__(256) void k_scatter(
    const int* __restrict__ src, const int* __restrict__ dst,
    const int* __restrict__ rank,
    const float* __restrict__ a_dst_arr, const float* __restrict__ a_src_arr,
    const float* __restrict__ Ab, uint_t* __restrict__ csr, int E)
{
    phase_scatter(src, dst, rank, a_dst_arr, a_src_arr, Ab[0], csr, E,
                  (int)(blockIdx.x * 256 + threadIdx.x), (int)(gridDim.x * 256));
}

__global__ __launch_bounds__(256) void k_agg(
    const int* __restrict__ cnt, const uint_t* __restrict__ csr,
    const uint_t* __restrict__ Whb2, float* __restrict__ out, int N)
{
    phase_agg(cnt, csr, Whb2, out, N,
              (int)((blockIdx.x * 256 + threadIdx.x) >> 6),
              (int)(gridDim.x * 4), (int)(threadIdx.x & 63));
}

// ---------------------------------------------------------------------------

extern "C" void kernel_launch(void* const* d_in, const int* in_sizes, int n_in,
                              void* d_out, int out_size, void* d_ws, size_t ws_size,
                              hipStream_t stream)
{
    const float* h   = (const float*)d_in[0];
    const float* W_w = (const float*)d_in[1];
    const float* W_b = (const float*)d_in[2];
    const float* A_w = (const float*)d_in[3];
    const float* A_b = (const float*)d_in[4];
    const int*   src = (const int*)d_in[5];
    const int*   dst = (const int*)d_in[6];
    float* out = (float*)d_out;

    int N = in_sizes[0] / IN_DIM;   // 50000
    int E = in_sizes[5];            // 800000

    // Workspace: Whb[N*64 u16] | a_dst[N] | a_src[N] | cnt[N] | rank[E] | csr[N*MAXDEG u32]
    ushort_t* Whb   = (ushort_t*)d_ws;
    float* a_dst_a  = (float*)(Whb + (size_t)N * OUT_DIM);
    float* a_src_a  = a_dst_a + N;
    int*   cnt      = (int*)(a_src_a + N);
    int*   rank     = cnt + N;
    uint_t* csr     = (uint_t*)(rank + E);

    // Clamp cooperative grid to what can actually be co-resident.
    int maxBlk = 0;
    hipError_t occ = hipOccupancyMaxActiveBlocksPerMultiprocessor(
        &maxBlk, (const void*)gat_all, 256, 0);
    int grid = COOP_BLKS;
    if (occ == hipSuccess && maxBlk > 0) {
        int cap = maxBlk * 256;   // 256 CUs on MI355X
        if (grid > cap) grid = cap;
    }

    void* args[] = {
        (void*)&h, (void*)&W_w, (void*)&W_b, (void*)&A_w, (void*)&A_b,
        (void*)&src, (void*)&dst,
        (void*)&Whb, (void*)&a_dst_a, (void*)&a_src_a,
        (void*)&cnt, (void*)&rank, (void*)&csr, (void*)&out,
        (void*)&N, (void*)&E
    };
    hipError_t err = hipLaunchCooperativeKernel((const void*)gat_all, dim3(grid),
                                                dim3(256), args, 0, stream);
    if (err != hipSuccess) {
        // Fallback: known-good multi-kernel path.
        (void)hipMemsetAsync(cnt, 0, (size_t)N * sizeof(int), stream);
        int HB = (E + 1023) / 1024;
        int ntiles = (N + 15) / 16;
        int PB = (ntiles + 3) / 4;
        k_fused<<<HB + PB, 256, 0, stream>>>(h, W_w, W_b, A_w, Whb,
                                             a_dst_a, a_src_a, N,
                                             dst, cnt, rank, E, HB);
        k_scatter<<<(E / 4 + 255) / 256, 256, 0, stream>>>(src, dst, rank,
                                                           a_dst_a, a_src_a,
                                                           A_b, csr, E);
        k_agg<<<(N + 3) / 4, 256, 0, stream>>>(cnt, csr, (const uint_t*)Whb, out, N);
    }
}

// Round 11
// 177.675 us; speedup vs baseline: 2.9172x; 2.9172x over previous
//
#include <hip/hip_runtime.h>
#include <hip/hip_fp16.h>

#define IN_DIM 128
#define OUT_DIM 64
#define MAXDEG 64   // padded-CSR stride; deg ~ Poisson(16), E[max over 50k nodes] ~ 40

typedef __attribute__((ext_vector_type(8))) short short8v;   // 8 bf16 (4 VGPRs)
typedef __attribute__((ext_vector_type(4))) float float4v;   // MFMA acc
typedef unsigned short ushort_t;
typedef unsigned int uint_t;

__device__ inline ushort_t f_to_bf16(float f) {
    uint_t x = __float_as_uint(f);
    uint_t r = (x + 0x7fffu + ((x >> 16) & 1u)) >> 16;   // RNE
    return (ushort_t)r;
}

// ---------------------------------------------------------------------------
// K1 (fused): blocks [0,SB) = single-pass scatter (src-only 2 B records, so it
// does NOT depend on proj); blocks [SB,...) = MFMA projection.
// Scatter: pos = atomicAdd(&cnt[dst]); csr2[dst*MAXDEG+pos] = (ushort)src.
// Proj: one wave = 16 nodes x 64 dims, K=128 in 4 MFMA steps; W swizzled in LDS.
// MFMA layouts (m89-verified): A[m=lane&15][k=quad*8+j], B[k=quad*8+j][n=lane&15],
// C/D col=lane&15, row=quad*4+reg.
// ---------------------------------------------------------------------------
__global__ __launch_bounds__(256) void k_fused(
    const float* __restrict__ h, const float* __restrict__ W,
    const float* __restrict__ Wb, const float* __restrict__ Aw,
    ushort_t* __restrict__ Whb, float* __restrict__ a_dst_arr,
    float* __restrict__ a_src_arr, int N,
    const int* __restrict__ src, const int* __restrict__ dst,
    int* __restrict__ cnt, ushort_t* __restrict__ csr2, int E, int SB)
{
    __shared__ ushort_t Wl[16 * 64 * 8];   // 16 KB (proj blocks only)
    const int t = threadIdx.x;

    if ((int)blockIdx.x < SB) {
        // ---- single-pass scatter: 4 edges/thread, 4 independent atomic chains ----
        int base = ((int)blockIdx.x * 256 + t) * 4;
        if (base + 4 <= E) {
            int4 s4 = *(const int4*)&src[base];
            int4 d4 = *(const int4*)&dst[base];
            int p0 = atomicAdd(&cnt[d4.x], 1);
            int p1 = atomicAdd(&cnt[d4.y], 1);
            int p2 = atomicAdd(&cnt[d4.z], 1);
            int p3 = atomicAdd(&cnt[d4.w], 1);
            csr2[d4.x * MAXDEG + p0] = (ushort_t)s4.x;
            csr2[d4.y * MAXDEG + p1] = (ushort_t)s4.y;
            csr2[d4.z * MAXDEG + p2] = (ushort_t)s4.z;
            csr2[d4.w * MAXDEG + p3] = (ushort_t)s4.w;
        } else {
            for (int e = base; e < E; e++) {
                int p = atomicAdd(&cnt[dst[e]], 1);
                csr2[dst[e] * MAXDEG + p] = (ushort_t)src[e];
            }
        }
        return;
    }

    // ---- MFMA projection ----
    stage_w: ;
    {
        int f = t * 32;
        #pragma unroll
        for (int i = 0; i < 32; i++, f++) {
            int frag = f >> 9;
            int ln   = (f >> 3) & 63;
            int j    = f & 7;
            int k    = (frag >> 2) * 32 + (ln >> 4) * 8 + j;
            int d    = (frag & 3) * 16 + (ln & 15);
            Wl[f] = f_to_bf16(W[k * OUT_DIM + d]);
        }
    }
    __syncthreads();

    const int lane = t & 63;
    const int quad = lane >> 4;
    const int col  = lane & 15;
    const int pb   = (int)blockIdx.x - SB;
    const int node0 = (pb * 4 + (t >> 6)) * 16;
    if (node0 >= N) return;

    const int rowc = min(node0 + col, N - 1);   // clamp for ragged tail
    const float* __restrict__ arow = h + (size_t)rowc * IN_DIM;

    float4v acc[4];
    #pragma unroll
    for (int db = 0; db < 4; db++) acc[db] = (float4v){0.f, 0.f, 0.f, 0.f};

    #pragma unroll
    for (int kb = 0; kb < 4; kb++) {
        const float* ap = arow + kb * 32 + quad * 8;
        float4 a0 = *(const float4*)ap;
        float4 a1 = *(const float4*)(ap + 4);
        union { short8v v; ushort_t u[8]; } af;
        af.u[0] = f_to_bf16(a0.x); af.u[1] = f_to_bf16(a0.y);
        af.u[2] = f_to_bf16(a0.z); af.u[3] = f_to_bf16(a0.w);
        af.u[4] = f_to_bf16(a1.x); af.u[5] = f_to_bf16(a1.y);
        af.u[6] = f_to_bf16(a1.z); af.u[7] = f_to_bf16(a1.w);
        #pragma unroll
        for (int db = 0; db < 4; db++) {
            short8v bf = *(const short8v*)&Wl[(((kb << 2) | db) * 64 + lane) * 8];
            acc[db] = __builtin_amdgcn_mfma_f32_16x16x32_bf16(af.v, bf, acc[db], 0, 0, 0);
        }
    }

    float pd[4] = {0.f, 0.f, 0.f, 0.f};
    float ps[4] = {0.f, 0.f, 0.f, 0.f};
    #pragma unroll
    for (int db = 0; db < 4; db++) {
        float wbv = Wb[db * 16 + col];
        float awd = Aw[db * 16 + col];
        float aws = Aw[OUT_DIM + db * 16 + col];
        #pragma unroll
        for (int r = 0; r < 4; r++) {
            float v = acc[db][r] + wbv;
            int node = node0 + quad * 4 + r;
            if (node < N)
                Whb[(size_t)node * OUT_DIM + db * 16 + col] = f_to_bf16(v);
            pd[r] = fmaf(v, awd, pd[r]);
            ps[r] = fmaf(v, aws, ps[r]);
        }
    }
    #pragma unroll
    for (int r = 0; r < 4; r++) {
        float d_ = pd[r], s_ = ps[r];
        #pragma unroll
        for (int off = 1; off < 16; off <<= 1) {
            d_ += __shfl_xor(d_, off);
            s_ += __shfl_xor(s_, off);
        }
        int node = node0 + quad * 4 + r;
        if (col == 0 && node < N) {
            a_dst_arr[node] = d_;
            a_src_arr[node] = s_;
        }
    }
}

// ---------------------------------------------------------------------------
// K2: gather-aggregate, one wave per node. Half-wave (el) per edge group of 4;
// dl = dim pair. Weight recomputed inline: w = exp(leaky(a_dst[u]+a_src[s]+ab))
// (fp32-exact; a_src[s] is an L2-resident broadcast load).
// ---------------------------------------------------------------------------
__global__ __launch_bounds__(256) void k_agg(
    const int* __restrict__ cnt, const ushort_t* __restrict__ csr2,
    const uint_t* __restrict__ Whb2,
    const float* __restrict__ a_dst_arr, const float* __restrict__ a_src_arr,
    const float* __restrict__ Ab, float* __restrict__ out, int N)
{
    int node = (int)((blockIdx.x * blockDim.x + threadIdx.x) >> 6);
    int lane = threadIdx.x & 63;
    if (node >= N) return;
    int u = __builtin_amdgcn_readfirstlane(node);
    int deg = cnt[u];
    const ushort_t* __restrict__ seg = csr2 + (size_t)u * MAXDEG;
    const float au = a_dst_arr[u] + Ab[0];   // wave-uniform

    const int el = lane >> 5;   // half-wave: edge-group slot
    const int dl = lane & 31;   // dim pair (dims 2*dl, 2*dl+1)

    float accx = 0.f, accy = 0.f, wsum = 0.f;
    int j = 0;
    for (; j + 8 <= deg; j += 8) {
        // half-wave el handles records [j+el*4, j+el*4+4): one 8 B broadcast load
        ushort4 r4 = *(const ushort4*)&seg[j + el * 4];
        ushort_t rr[4] = {r4.x, r4.y, r4.z, r4.w};
        #pragma unroll
        for (int b = 0; b < 4; b++) {
            int s = (int)rr[b];
            float v = au + a_src_arr[s];
            v = (v > 0.0f) ? v : 0.2f * v;
            float w = __expf(v);
            uint_t p = Whb2[(size_t)s * 32 + dl];
            float fx = __uint_as_float(p << 16);
            float fy = __uint_as_float(p & 0xffff0000u);
            accx = fmaf(w, fx, accx);
            accy = fmaf(w, fy, accy);
            wsum += w;
        }
    }
    for (; j < deg; j += 2) {
        int e = j + el;
        if (e < deg) {
            int s = (int)seg[e];
            float v = au + a_src_arr[s];
            v = (v > 0.0f) ? v : 0.2f * v;
            float w = __expf(v);
            uint_t p = Whb2[(size_t)s * 32 + dl];
            float fx = __uint_as_float(p << 16);
            float fy = __uint_as_float(p & 0xffff0000u);
            accx = fmaf(w, fx, accx);
            accy = fmaf(w, fy, accy);
            wsum += w;
        }
    }

    // Combine the two half-wave slots.
    accx += __shfl_xor(accx, 32);
    accy += __shfl_xor(accy, 32);
    wsum += __shfl_xor(wsum, 32);

    float inv = (deg > 0) ? 1.0f / wsum : 0.0f;
    if (lane < 32) {
        float2 o = make_float2(accx * inv, accy * inv);
        *(float2*)&out[(size_t)u * OUT_DIM + dl * 2] = o;
    }
}

// ---------------------------------------------------------------------------

extern "C" void kernel_launch(void* const* d_in, const int* in_sizes, int n_in,
                              void* d_out, int out_size, void* d_ws, size_t ws_size,
                              hipStream_t stream)
{
    const float* h   = (const float*)d_in[0];
    const float* W_w = (const float*)d_in[1];
    const float* W_b = (const float*)d_in[2];
    const float* A_w = (const float*)d_in[3];
    const float* A_b = (const float*)d_in[4];
    const int*   src = (const int*)d_in[5];
    const int*   dst = (const int*)d_in[6];
    float* out = (float*)d_out;

    int N = in_sizes[0] / IN_DIM;   // 50000
    int E = in_sizes[5];            // 800000

    // Workspace: Whb[N*64 u16] | a_dst[N] | a_src[N] | cnt[N] | csr2[N*MAXDEG u16]
    ushort_t* Whb   = (ushort_t*)d_ws;
    float* a_dst_a  = (float*)(Whb + (size_t)N * OUT_DIM);
    float* a_src_a  = a_dst_a + N;
    int*   cnt      = (int*)(a_src_a + N);
    ushort_t* csr2  = (ushort_t*)(cnt + N);

    (void)hipMemsetAsync(cnt, 0, (size_t)N * sizeof(int), stream);

    {   // K1: fused single-pass scatter (blocks [0,SB)) + MFMA proj (rest)
        int SB = (E + 1023) / 1024;          // 4 edges/thread
        int ntiles = (N + 15) / 16;
        int PB = (ntiles + 3) / 4;           // 4 waves (tiles) per block
        k_fused<<<SB + PB, 256, 0, stream>>>(h, W_w, W_b, A_w, Whb,
                                             a_dst_a, a_src_a, N,
                                             src, dst, cnt, csr2, E, SB);
    }
    {   // K2: gather-aggregate (one wave per node)
        int grid = (N + 3) / 4;
        k_agg<<<grid, 256, 0, stream>>>(cnt, csr2, (const uint_t*)Whb,
                                        a_dst_a, a_src_a, A_b, out, N);
    }
}